// Round 2
// baseline (408.014 us; speedup 1.0000x reference)
//
#include <hip/hip_runtime.h>
#include <stdint.h>

// HOPELoRALayer — B=8, S=4096, D=1024, R_TOT=104. fp32 I/O; bf16 MFMA GEMM.
// Reductions:
//   gate_scale = mean(softmax over 3) == 1/3 exactly -> gate net dead code.
//   out = X @ (base_w + (1/3) pu@diag(1+mem)@pd)^T + base_b
// mem==0 (fresh state) -> batch-independent W0; general case kept via
// per-batch flag + Weff (computed only if mem[b]!=0).
//
// R5 change: R4's phases serialized LDS-pipe vs MFMA-pipe (read frags ->
// barrier -> consume; MfmaUtil 30%, ~2400cy/K-tile vs 1240 MFMA floor).
// New schedule issues every ds_read ONE PHASE BEFORE its consuming MFMA so
// the LDS pipe (~1150cy/tile/CU) hides under the MFMA cluster:
//   ph0: STAGE_A(kt+2) | read af[4..7](cur) | MFMA mi0..3 (frags from prev ph)
//        vmcnt(2) + barrier            (tile kt+1 published to all waves)
//   ph1: STAGE_B(kt+2) | prefetch af[0..3],bf[0..3] of buf(kt+1) | MFMA mi4..7
//   (no 2nd barrier: within the 1-barrier skew window, writes target buffer
//    (kt-1)&3 / (kt+2)&3 while reads touch (kt+1)&3 — disjoint; 4-deep ring)
// Barriers: 128/block -> 32. vmcnt never drained mid-loop (A(kt+2) stays in
// flight). Peak live frags 16 (64 VGPR) + 128 acc = fits 2 waves/SIMD.
// convert_x: 16384 tiny blocks -> 2048 blocks x 64 floats/thread.

typedef unsigned short ushort_t;
typedef unsigned short us8 __attribute__((ext_vector_type(8)));
typedef short short8 __attribute__((ext_vector_type(8)));
typedef float f32x4 __attribute__((ext_vector_type(4)));

__device__ __forceinline__ ushort_t f2b(float f) {  // RNE fp32->bf16
  union { float f; uint32_t i; } v; v.f = f;
  uint32_t lsb = (v.i >> 16) & 1u;
  v.i += 0x7fffu + lsb;
  return (ushort_t)(v.i >> 16);
}

__device__ __forceinline__ void async16(const void* g, void* l) {
  __builtin_amdgcn_global_load_lds(
      (const __attribute__((address_space(1))) void*)g,
      (__attribute__((address_space(3))) void*)l, 16, 0, 0);
}

// ---- x fp32 -> bf16, batch->XCD matched to gemm ----------------------------
__global__ __launch_bounds__(256) void convert_x(const float* __restrict__ x,
                                                 ushort_t* __restrict__ xb) {
  const int flat = blockIdx.x;     // 2048 blocks
  const int b = flat & 7;          // XCD-matched batch
  const int c0 = flat >> 3;        // 0..255, 16K-float slab within batch
  const size_t base = (size_t)b * 4194304 + (size_t)c0 * 16384;
#pragma unroll 2
  for (int u = 0; u < 8; ++u) {
    const size_t i = base + u * 2048 + threadIdx.x * 8;
    f32x4 a0 = *(const f32x4*)(x + i);
    f32x4 a1 = *(const f32x4*)(x + i + 4);
    us8 o;
#pragma unroll
    for (int j = 0; j < 4; j++) { o[j] = f2b(a0[j]); o[4 + j] = f2b(a1[j]); }
    *(us8*)(xb + i) = o;
  }
}

// ---- merged prep: y==0 -> W0 row; y=1..8 -> flags[b] + Weff row if mem!=0 --
__global__ __launch_bounds__(128) void prep(const float* __restrict__ base_w,
                                            const float* __restrict__ pu_w,
                                            const float* __restrict__ pd_w,
                                            const float* __restrict__ mf,
                                            const float* __restrict__ mm,
                                            const float* __restrict__ ms,
                                            ushort_t* __restrict__ W0,
                                            ushort_t* __restrict__ Weff,
                                            int* __restrict__ flags) {
  const int o = blockIdx.x, y = blockIdx.y, t = threadIdx.x;
  __shared__ float spu[104];
  __shared__ int sflag;
  ushort_t* dst;

  if (y == 0) {
    if (t < 104) spu[t] = pu_w[o * 104 + t] * (1.0f / 3.0f);
    dst = W0 + o * 1024;
    __syncthreads();
  } else {
    const int b = y - 1;
    if (t == 0) sflag = 0;
    __syncthreads();
    float mv = 0.0f;
    if (t < 104) {
      mv = (t < 8) ? mf[b * 8 + t]
         : (t < 40) ? mm[b * 32 + (t - 8)]
                    : ms[b * 64 + (t - 40)];
      if (mv != 0.0f) sflag = 1;
      spu[t] = pu_w[o * 104 + t] * (1.0f + mv) * (1.0f / 3.0f);
    }
    __syncthreads();
    if (o == 0 && t == 0) flags[b] = sflag;
    if (!sflag) return;  // block-uniform
    dst = Weff + ((size_t)b << 20) + o * 1024;
  }

  const int d0 = t * 8;
  float acc[8];
  f32x4 b0 = *(const f32x4*)(base_w + o * 1024 + d0);
  f32x4 b1 = *(const f32x4*)(base_w + o * 1024 + d0 + 4);
#pragma unroll
  for (int j = 0; j < 4; j++) { acc[j] = b0[j]; acc[4 + j] = b1[j]; }
  for (int r = 0; r < 104; r++) {
    f32x4 p0 = *(const f32x4*)(pd_w + r * 1024 + d0);
    f32x4 p1 = *(const f32x4*)(pd_w + r * 1024 + d0 + 4);
    float s = spu[r];
#pragma unroll
    for (int j = 0; j < 4; j++) { acc[j] += s * p0[j]; acc[4 + j] += s * p1[j]; }
  }
  us8 ov;
#pragma unroll
  for (int j = 0; j < 8; j++) ov[j] = f2b(acc[j]);
  *(us8*)(dst + d0) = ov;
}

// ---- main GEMM: out[b, m, n] = sum_k xb[b,m,k] * W[n,k] + base_b[n] --------
// 256x256 tile, BK=32. 8 waves (2M x 4N), per-wave 128x64 out = 8x4 frags of
// mfma_f32_16x16x32_bf16. Grid 512 blocks: b = flat&7 (batch==XCD), then
// bn-inner/bm-outer so 4 consecutive blocks on an XCD share the A panel in L2.
__global__ __launch_bounds__(512, 2) void gemm256(
    const ushort_t* __restrict__ xb, const float* __restrict__ base_b,
    const ushort_t* __restrict__ W0, const ushort_t* __restrict__ Weff,
    const int* __restrict__ flags, float* __restrict__ out) {
  const int flat = blockIdx.x;
  const int b  = flat & 7;                 // batch == XCD
  const int i  = flat >> 3;                // 0..63
  const int bm = i >> 2;                   // 0..15 (M tile)
  const int bn = i & 3;                    // 0..3  (N tile)

  const ushort_t* W = flags[b] ? (Weff + ((size_t)b << 20)) : W0;

  // 4-deep ring: per buffer A[256][32] (16KiB) + B[256][32] (16KiB) = 32KiB
  __shared__ __align__(16) char lds[4 * 32768];  // 128 KiB

  const int t = threadIdx.x;
  const int w = t >> 6, l = t & 63;
  const int wr = w >> 2, wc = w & 3;       // wave -> (M half, N quarter)
  const int row16 = l & 15, quad = l >> 4;

  // ---- staging addresses (global source carries the inverse swizzle) ----
  const int srow = w * 16 + (l >> 2);
  const int scol = (((l & 3) ^ ((l >> 3) & 3))) * 8;   // bf16 units
  const ushort_t* gA = xb + (((size_t)b * 4096 + bm * 256 + srow) << 10) + scol;
  const ushort_t* gB = W + (((size_t)(bn * 256 + srow)) << 10) + scol;

  // ---- ds_read addressing (applies the same XOR on the k-slot) ----
  const int qsw = (quad ^ ((row16 >> 1) & 3)) * 16;          // byte slot
  const int aoff = (wr * 128 + row16) * 64 + qsw;            // + mi*1024
  const int boff = 16384 + (wc * 64 + row16) * 64 + qsw;     // + ni*1024

#define STAGE_A(kt)                                                       \
  {                                                                       \
    const ushort_t* g_ = gA + (kt) * 32;                                  \
    char* d_ = lds + ((kt) & 3) * 32768 + w * 1024;                       \
    async16(g_, d_);                                                      \
    async16(g_ + (128 << 10), d_ + 8192);                                 \
  }
#define STAGE_B(kt)                                                       \
  {                                                                       \
    const ushort_t* g_ = gB + (kt) * 32;                                  \
    char* d_ = lds + ((kt) & 3) * 32768 + 16384 + w * 1024;               \
    async16(g_, d_);                                                      \
    async16(g_ + (128 << 10), d_ + 8192);                                 \
  }

  f32x4 acc[8][4] = {};
  short8 af[2][4], bf[2][4], af2[4];

  // prologue: stage tiles 0,1; wait for tile 0 (A1,B1 stay in flight);
  // preload tile-0 frags for mi0..3.
  STAGE_A(0) STAGE_B(0) STAGE_A(1) STAGE_B(1)
  asm volatile("s_waitcnt vmcnt(4)" ::: "memory");
  __builtin_amdgcn_s_barrier();
#pragma unroll
  for (int mi = 0; mi < 4; ++mi)
    af[0][mi] = *(const short8*)(lds + aoff + mi * 1024);
#pragma unroll
  for (int ni = 0; ni < 4; ++ni)
    bf[0][ni] = *(const short8*)(lds + boff + ni * 1024);

#pragma unroll 4
  for (int kt = 0; kt < 32; ++kt) {
    const int p = kt & 1;                              // static under unroll 4
    const char* cur = lds + (kt & 3) * 32768;
    const char* nxt = lds + ((kt + 1) & 3) * 32768;

    // ---- phase 0: stage A(kt+2) | read af[4..7](cur) | MFMA mi0..3 ----
    if (kt < 30) STAGE_A(kt + 2)
#pragma unroll
    for (int j = 0; j < 4; ++j)
      af2[j] = *(const short8*)(cur + aoff + (4 + j) * 1024);
    __builtin_amdgcn_s_setprio(1);
#pragma unroll
    for (int mi = 0; mi < 4; ++mi)
#pragma unroll
      for (int ni = 0; ni < 4; ++ni)
        acc[mi][ni] = __builtin_amdgcn_mfma_f32_16x16x32_bf16(af[p][mi], bf[p][ni],
                                                              acc[mi][ni], 0, 0, 0);
    __builtin_amdgcn_s_setprio(0);

    // ---- tile sync: own kt+1 loads drained (A(kt+2) stays in flight),
    //      then barrier publishes buf(kt+1) across waves
    if (kt < 30) {
      asm volatile("s_waitcnt vmcnt(2)" ::: "memory");
    } else if (kt == 30) {
      asm volatile("s_waitcnt vmcnt(0)" ::: "memory");
    }
    __builtin_amdgcn_s_barrier();

    // ---- phase 1: stage B(kt+2) | prefetch next-tile frags | MFMA mi4..7 ----
    if (kt < 30) STAGE_B(kt + 2)
    if (kt < 31) {
#pragma unroll
      for (int mi = 0; mi < 4; ++mi)
        af[p ^ 1][mi] = *(const short8*)(nxt + aoff + mi * 1024);
#pragma unroll
      for (int ni = 0; ni < 4; ++ni)
        bf[p ^ 1][ni] = *(const short8*)(nxt + boff + ni * 1024);
    }
    __builtin_amdgcn_s_setprio(1);
#pragma unroll
    for (int mi = 0; mi < 4; ++mi)
#pragma unroll
      for (int ni = 0; ni < 4; ++ni)
        acc[4 + mi][ni] = __builtin_amdgcn_mfma_f32_16x16x32_bf16(af2[mi], bf[p][ni],
                                                                  acc[4 + mi][ni], 0, 0, 0);
    __builtin_amdgcn_s_setprio(0);
    // no barrier here: next ph0 writes buf (kt-1)&3, reads buf (kt+1)&3 —
    // disjoint from anything touched in this phase under 1-barrier skew.
  }

  // epilogue: C/D layout col=lane&15, row=quad*4+reg (m89-verified)
#pragma unroll
  for (int ni = 0; ni < 4; ++ni) {
    const int col = bn * 256 + wc * 64 + ni * 16 + row16;
    const float bb = base_b[col];
#pragma unroll
    for (int mi = 0; mi < 8; ++mi) {
      const int row = bm * 256 + wr * 128 + mi * 16 + quad * 4;
      float* po = out + (((size_t)b * 4096 + row) << 10) + col;
#pragma unroll
      for (int i2 = 0; i2 < 4; ++i2)
        po[(size_t)i2 << 10] = acc[mi][ni][i2] + bb;
    }
  }
#undef STAGE_A
#undef STAGE_B
}

extern "C" void kernel_launch(void* const* d_in, const int* in_sizes, int n_in,
                              void* d_out, int out_size, void* d_ws, size_t ws_size,
                              hipStream_t stream) {
  const float* x  = (const float*)d_in[0];
  const float* mf = (const float*)d_in[1];
  const float* mm = (const float*)d_in[2];
  const float* ms = (const float*)d_in[3];
  const float* base_w = (const float*)d_in[4];
  const float* base_b = (const float*)d_in[5];
  const float* pd_w = (const float*)d_in[6];
  const float* pu_w = (const float*)d_in[7];
  // d_in[8..11] (gate net) are mathematically dead: mean(softmax_3) == 1/3.

  char* ws = (char*)d_ws;
  int* flags     = (int*)ws;                                   // 32 B
  ushort_t* W0   = (ushort_t*)(ws + 4096);                     // 2 MiB
  ushort_t* xb   = (ushort_t*)(ws + 4096 + (2u << 20));        // 64 MiB
  ushort_t* Weff = (ushort_t*)(ws + 4096 + (2u << 20) + (64u << 20));  // 16 MiB, cold

  prep<<<dim3(1024, 9), 128, 0, stream>>>(base_w, pu_w, pd_w, mf, mm, ms,
                                          W0, Weff, flags);
  convert_x<<<2048, 256, 0, stream>>>(x, xb);
  gemm256<<<512, 512, 0, stream>>>(xb, base_b, W0, Weff, flags, (float*)d_out);
}

// Round 3
// 344.250 us; speedup vs baseline: 1.1852x; 1.1852x over previous
//
#include <hip/hip_runtime.h>
#include <stdint.h>

// HOPELoRALayer — B=8, S=4096, D=1024, R_TOT=104. fp32 I/O; bf16 MFMA GEMM.
// Reductions:
//   gate_scale = mean(softmax over 3) == 1/3 exactly -> gate net dead code.
//   out = X @ (base_w + (1/3) pu@diag(1+mem)@pd)^T + base_b
// mem==0 (fresh state) -> batch-independent W0; general case kept via
// per-batch flag + Weff (computed only if mem[b]!=0).
//
// R6 change (post-mortem of R5 spill regression -> revert frag dbuf, revert
// convert_x to 16384-block version):
//   R4's 30% MfmaUtil ~= serial sum of pipe demands (MFMA 1240cy + LDS-read
//   1150cy + staging per tile) -> the read/MFMA overlap never happened.
//   Two fixes, zero extra registers:
//   1. sched_barrier(0) pins the ds_read group BEFORE s_barrier (s_barrier is
//      not a compiler fence; hipcc can sink loads past it, serializing the
//      phase). With reads pinned, all 8 waves' reads queue in the LDS FIFO
//      across the barrier and drain while earlier waves MFMA (m201 mechanism).
//   2. boundary wait vmcnt(4) not vmcnt(2): only A/B(kt+1) must be complete;
//      R4's vmcnt(2) also waited A(kt+2) issued ~1 phase earlier -> periodic
//      HBM-latency stall.
//   Plus: balanced read split 8/4 (was 10/2), 3 barriers/tile (was 4).

typedef unsigned short ushort_t;
typedef unsigned short us8 __attribute__((ext_vector_type(8)));
typedef short short8 __attribute__((ext_vector_type(8)));
typedef float f32x4 __attribute__((ext_vector_type(4)));

__device__ __forceinline__ ushort_t f2b(float f) {  // RNE fp32->bf16
  union { float f; uint32_t i; } v; v.f = f;
  uint32_t lsb = (v.i >> 16) & 1u;
  v.i += 0x7fffu + lsb;
  return (ushort_t)(v.i >> 16);
}

__device__ __forceinline__ void async16(const void* g, void* l) {
  __builtin_amdgcn_global_load_lds(
      (const __attribute__((address_space(1))) void*)g,
      (__attribute__((address_space(3))) void*)l, 16, 0, 0);
}

// ---- x fp32 -> bf16, batch->XCD matched to gemm (R4 version, measured) -----
__global__ __launch_bounds__(256) void convert_x(const float* __restrict__ x,
                                                 ushort_t* __restrict__ xb) {
  const int flat = blockIdx.x;
  const int b = flat & 7;          // XCD-matched batch
  const int c = flat >> 3;         // 0..2047 chunk within batch
  const size_t i = (((size_t)b * 2048 + c) * 256 + threadIdx.x) * 8;
  f32x4 a0 = *(const f32x4*)(x + i);
  f32x4 a1 = *(const f32x4*)(x + i + 4);
  us8 o;
#pragma unroll
  for (int j = 0; j < 4; j++) { o[j] = f2b(a0[j]); o[4 + j] = f2b(a1[j]); }
  *(us8*)(xb + i) = o;
}

// ---- merged prep: y==0 -> W0 row; y=1..8 -> flags[b] + Weff row if mem!=0 --
__global__ __launch_bounds__(128) void prep(const float* __restrict__ base_w,
                                            const float* __restrict__ pu_w,
                                            const float* __restrict__ pd_w,
                                            const float* __restrict__ mf,
                                            const float* __restrict__ mm,
                                            const float* __restrict__ ms,
                                            ushort_t* __restrict__ W0,
                                            ushort_t* __restrict__ Weff,
                                            int* __restrict__ flags) {
  const int o = blockIdx.x, y = blockIdx.y, t = threadIdx.x;
  __shared__ float spu[104];
  __shared__ int sflag;
  ushort_t* dst;

  if (y == 0) {
    if (t < 104) spu[t] = pu_w[o * 104 + t] * (1.0f / 3.0f);
    dst = W0 + o * 1024;
    __syncthreads();
  } else {
    const int b = y - 1;
    if (t == 0) sflag = 0;
    __syncthreads();
    float mv = 0.0f;
    if (t < 104) {
      mv = (t < 8) ? mf[b * 8 + t]
         : (t < 40) ? mm[b * 32 + (t - 8)]
                    : ms[b * 64 + (t - 40)];
      if (mv != 0.0f) sflag = 1;
      spu[t] = pu_w[o * 104 + t] * (1.0f + mv) * (1.0f / 3.0f);
    }
    __syncthreads();
    if (o == 0 && t == 0) flags[b] = sflag;
    if (!sflag) return;  // block-uniform
    dst = Weff + ((size_t)b << 20) + o * 1024;
  }

  const int d0 = t * 8;
  float acc[8];
  f32x4 b0 = *(const f32x4*)(base_w + o * 1024 + d0);
  f32x4 b1 = *(const f32x4*)(base_w + o * 1024 + d0 + 4);
#pragma unroll
  for (int j = 0; j < 4; j++) { acc[j] = b0[j]; acc[4 + j] = b1[j]; }
  for (int r = 0; r < 104; r++) {
    f32x4 p0 = *(const f32x4*)(pd_w + r * 1024 + d0);
    f32x4 p1 = *(const f32x4*)(pd_w + r * 1024 + d0 + 4);
    float s = spu[r];
#pragma unroll
    for (int j = 0; j < 4; j++) { acc[j] += s * p0[j]; acc[4 + j] += s * p1[j]; }
  }
  us8 ov;
#pragma unroll
  for (int j = 0; j < 8; j++) ov[j] = f2b(acc[j]);
  *(us8*)(dst + d0) = ov;
}

// ---- main GEMM: out[b, m, n] = sum_k xb[b,m,k] * W[n,k] + base_b[n] --------
// 256x256 tile, BK=32. 8 waves (2M x 4N), per-wave 128x64 out = 8x4 frags of
// mfma_f32_16x16x32_bf16. Grid 512 blocks: b = flat&7 (batch==XCD).
__global__ __launch_bounds__(512, 2) void gemm256(
    const ushort_t* __restrict__ xb, const float* __restrict__ base_b,
    const ushort_t* __restrict__ W0, const ushort_t* __restrict__ Weff,
    const int* __restrict__ flags, float* __restrict__ out) {
  const int flat = blockIdx.x;
  const int b  = flat & 7;                 // batch == XCD
  const int i  = flat >> 3;                // 0..63
  const int bm = i >> 2;                   // 0..15 (M tile)
  const int bn = i & 3;                    // 0..3  (N tile)

  const ushort_t* W = flags[b] ? (Weff + ((size_t)b << 20)) : W0;

  // 4-deep ring: per buffer A[256][32] (16KiB) + B[256][32] (16KiB) = 32KiB
  __shared__ __align__(16) char lds[4 * 32768];  // 128 KiB

  const int t = threadIdx.x;
  const int w = t >> 6, l = t & 63;
  const int wr = w >> 2, wc = w & 3;       // wave -> (M half, N quarter)
  const int row16 = l & 15, quad = l >> 4;

  // ---- staging addresses (global source carries the inverse swizzle) ----
  const int srow = w * 16 + (l >> 2);
  const int scol = (((l & 3) ^ ((l >> 3) & 3))) * 8;   // bf16 units
  const ushort_t* gA = xb + (((size_t)b * 4096 + bm * 256 + srow) << 10) + scol;
  const ushort_t* gB = W + (((size_t)(bn * 256 + srow)) << 10) + scol;

  // ---- ds_read addressing (applies the same XOR on the k-slot) ----
  const int qsw = (quad ^ ((row16 >> 1) & 3)) * 16;          // byte slot
  const int aoff = (wr * 128 + row16) * 64 + qsw;            // + mi*1024
  const int boff = 16384 + (wc * 64 + row16) * 64 + qsw;     // + ni*1024

#define STAGE_A(kt)                                                       \
  {                                                                       \
    const ushort_t* g_ = gA + (kt) * 32;                                  \
    char* d_ = lds + ((kt) & 3) * 32768 + w * 1024;                       \
    async16(g_, d_);                                                      \
    async16(g_ + (128 << 10), d_ + 8192);                                 \
  }
#define STAGE_B(kt)                                                       \
  {                                                                       \
    const ushort_t* g_ = gB + (kt) * 32;                                  \
    char* d_ = lds + ((kt) & 3) * 32768 + 16384 + w * 1024;               \
    async16(g_, d_);                                                      \
    async16(g_ + (128 << 10), d_ + 8192);                                 \
  }

  f32x4 acc[8][4] = {};

  // prologue: stage tiles 0,1; wait tile 0 only (A1,B1 = 4 loads in flight)
  STAGE_A(0) STAGE_B(0) STAGE_A(1) STAGE_B(1)
  asm volatile("s_waitcnt vmcnt(4)" ::: "memory");
  __builtin_amdgcn_s_barrier();

  for (int kt = 0; kt < 32; ++kt) {
    const char* cur = lds + (kt & 3) * 32768;

    // ---- phase 0: read af0..3 + bf0..3 (8) | stage A(kt+2) | 16 MFMA ----
    short8 af[4], bf[4];
#pragma unroll
    for (int mi = 0; mi < 4; ++mi)
      af[mi] = *(const short8*)(cur + aoff + mi * 1024);
#pragma unroll
    for (int ni = 0; ni < 4; ++ni)
      bf[ni] = *(const short8*)(cur + boff + ni * 1024);
    if (kt < 30) STAGE_A(kt + 2)
    __builtin_amdgcn_sched_barrier(0);   // pin reads+stage BEFORE the barrier
    __builtin_amdgcn_s_barrier();
    __builtin_amdgcn_s_setprio(1);
#pragma unroll
    for (int mi = 0; mi < 4; ++mi)
#pragma unroll
      for (int ni = 0; ni < 4; ++ni)
        acc[mi][ni] = __builtin_amdgcn_mfma_f32_16x16x32_bf16(af[mi], bf[ni],
                                                              acc[mi][ni], 0, 0, 0);
    __builtin_amdgcn_s_setprio(0);
    // no barrier here: ph1 reads the same (published) buffer — no hazard.

    // ---- phase 1: read af4..7 (4) | stage B(kt+2) | 16 MFMA ----
    short8 af2[4];
#pragma unroll
    for (int mi = 0; mi < 4; ++mi)
      af2[mi] = *(const short8*)(cur + aoff + (4 + mi) * 1024);
    if (kt < 30) STAGE_B(kt + 2)
    __builtin_amdgcn_sched_barrier(0);   // pin reads+stage BEFORE the barrier
    __builtin_amdgcn_s_barrier();
    __builtin_amdgcn_s_setprio(1);
#pragma unroll
    for (int mi = 0; mi < 4; ++mi)
#pragma unroll
      for (int ni = 0; ni < 4; ++ni)
        acc[4 + mi][ni] = __builtin_amdgcn_mfma_f32_16x16x32_bf16(af2[mi], bf[ni],
                                                                  acc[4 + mi][ni], 0, 0, 0);
    __builtin_amdgcn_s_setprio(0);

    // ---- K-tile boundary: wait ONLY for tile kt+1 (A/B(kt+2) = 4 loads
    //      stay in flight), then publish across waves.
    if (kt < 30) {
      asm volatile("s_waitcnt vmcnt(4)" ::: "memory");
    } else if (kt == 30) {
      asm volatile("s_waitcnt vmcnt(0)" ::: "memory");
    }
    __builtin_amdgcn_s_barrier();
  }

  // epilogue: C/D layout col=lane&15, row=quad*4+reg (m89-verified)
#pragma unroll
  for (int ni = 0; ni < 4; ++ni) {
    const int col = bn * 256 + wc * 64 + ni * 16 + row16;
    const float bb = base_b[col];
#pragma unroll
    for (int mi = 0; mi < 8; ++mi) {
      const int row = bm * 256 + wr * 128 + mi * 16 + quad * 4;
      float* po = out + (((size_t)b * 4096 + row) << 10) + col;
#pragma unroll
      for (int i2 = 0; i2 < 4; ++i2)
        po[(size_t)i2 << 10] = acc[mi][ni][i2] + bb;
    }
  }
#undef STAGE_A
#undef STAGE_B
}

extern "C" void kernel_launch(void* const* d_in, const int* in_sizes, int n_in,
                              void* d_out, int out_size, void* d_ws, size_t ws_size,
                              hipStream_t stream) {
  const float* x  = (const float*)d_in[0];
  const float* mf = (const float*)d_in[1];
  const float* mm = (const float*)d_in[2];
  const float* ms = (const float*)d_in[3];
  const float* base_w = (const float*)d_in[4];
  const float* base_b = (const float*)d_in[5];
  const float* pd_w = (const float*)d_in[6];
  const float* pu_w = (const float*)d_in[7];
  // d_in[8..11] (gate net) are mathematically dead: mean(softmax_3) == 1/3.

  char* ws = (char*)d_ws;
  int* flags     = (int*)ws;                                   // 32 B
  ushort_t* W0   = (ushort_t*)(ws + 4096);                     // 2 MiB
  ushort_t* xb   = (ushort_t*)(ws + 4096 + (2u << 20));        // 64 MiB
  ushort_t* Weff = (ushort_t*)(ws + 4096 + (2u << 20) + (64u << 20));  // 16 MiB, cold

  prep<<<dim3(1024, 9), 128, 0, stream>>>(base_w, pu_w, pd_w, mf, mm, ms,
                                          W0, Weff, flags);
  convert_x<<<16384, 256, 0, stream>>>(x, xb);
  gemm256<<<512, 512, 0, stream>>>(xb, base_b, W0, Weff, flags, (float*)d_out);
}